// Round 2
// baseline (110.189 us; speedup 1.0000x reference)
//
#include <hip/hip_runtime.h>
#include <math.h>

// Soft-DTW (DILATE, alpha=1, gamma=0.01), B=64, N=512, F=1, n=511.
// R20 = R19 (single-wave-per-batch, 8 rows/lane) + R18's register-pinning
// discipline. R19 regressed (58us vs R18's ~32us) because the compiler,
// free of the PINF pins, shortened live ranges by scattering the 20
// ds_read_b64 window loads into the step stream (VGPR_Count=88 < ~105
// live), exposing ~120cy LDS latency per load (~50 cy/diag of stall).
// Fix: PINW40(XU) at chunk start forces the consuming buffer's loads to
// be complete (they were issued a full chunk = ~1600cy earlier); the next
// buffer's loads issue immediately after and are fenced from sinking by
// an asm memory clobber. Steps are then pure VALU: ~25 instr/diag * 2cy
// (wave64) ~= 50 cy/diag issue-bound.
//
// Recursion per diagonal d, cell c=0..7 (row 8l+c):
//   nv[c] = (dy[c] - dx[j-1])^2 + min3(prev2[c-1], prev1[c-1], prev1[c])
// Cross-lane only for c==0 via DPP wave_shr1 of r1_7 (1 DPP / 8 rows).
// Lane 0 injects INF; R[0][0]=0 seed rides r2_0. Invalid cells stay ~INF
// by construction (ulp(1e9)=64 absorbs u^2 increments).
//
// dx window: per chunk of 32 diagonals each lane needs 39 contiguous dx
// values (window idx w = k+7-c), kept in 40 regs, double-buffered (xa/xb),
// loaded as 20x ds_read_b64. Per-lane stride 8 floats (32B) => naive
// 16-way bank conflict; dxe replicated 4x at stride 1546 floats (+10
// banks/replica), lane uses replica (l>>2)&3 => residual 4-way across
// l,l+16,l+32,l+48 = wave64 b64 floor.

#define INF_F 1000000000.0f

// whole-wave shift right by 1; lane0 receives `oldv` (bound_ctrl=0 keeps old)
__device__ __forceinline__ float dpp_shr1_inj(float x, float oldv){
  int r = __builtin_amdgcn_update_dpp(__float_as_int(oldv), __float_as_int(x),
                                      0x138 /*WAVE_SHR1*/, 0xf, 0xf, false);
  return __int_as_float(r);
}
__device__ __forceinline__ float min3f(float a, float b, float c){
  float d;
  asm("v_min3_f32 %0, %1, %2, %3" : "=v"(d) : "v"(a), "v"(b), "v"(c));
  return d;
}
#define PINF(v) asm volatile("" : "+v"(v))

// load 40-float window (20 float2, even-aligned) into P##0..P##39
#define LOADW40(P, FB) { const float2* _p = dxw + (FB); \
  float2 a0=_p[0],a1=_p[1],a2=_p[2],a3=_p[3],a4=_p[4],a5=_p[5],a6=_p[6],a7=_p[7]; \
  float2 a8=_p[8],a9=_p[9],a10=_p[10],a11=_p[11],a12=_p[12],a13=_p[13]; \
  float2 a14=_p[14],a15=_p[15],a16=_p[16],a17=_p[17],a18=_p[18],a19=_p[19]; \
  P##0=a0.x;  P##1=a0.y;  P##2=a1.x;  P##3=a1.y;  P##4=a2.x;  P##5=a2.y; \
  P##6=a3.x;  P##7=a3.y;  P##8=a4.x;  P##9=a4.y;  P##10=a5.x; P##11=a5.y; \
  P##12=a6.x; P##13=a6.y; P##14=a7.x; P##15=a7.y; P##16=a8.x; P##17=a8.y; \
  P##18=a9.x; P##19=a9.y; P##20=a10.x;P##21=a10.y;P##22=a11.x;P##23=a11.y; \
  P##24=a12.x;P##25=a12.y;P##26=a13.x;P##27=a13.y;P##28=a14.x;P##29=a14.y; \
  P##30=a15.x;P##31=a15.y;P##32=a16.x;P##33=a16.y;P##34=a17.x;P##35=a17.y; \
  P##36=a18.x;P##37=a18.y;P##38=a19.x;P##39=a19.y; }

#define PINW40(P) { PINF(P##0); PINF(P##1); PINF(P##2); PINF(P##3); \
  PINF(P##4); PINF(P##5); PINF(P##6); PINF(P##7); PINF(P##8); PINF(P##9); \
  PINF(P##10); PINF(P##11); PINF(P##12); PINF(P##13); PINF(P##14); \
  PINF(P##15); PINF(P##16); PINF(P##17); PINF(P##18); PINF(P##19); \
  PINF(P##20); PINF(P##21); PINF(P##22); PINF(P##23); PINF(P##24); \
  PINF(P##25); PINF(P##26); PINF(P##27); PINF(P##28); PINF(P##29); \
  PINF(P##30); PINF(P##31); PINF(P##32); PINF(P##33); PINF(P##34); \
  PINF(P##35); PINF(P##36); PINF(P##37); PINF(P##38); PINF(P##39); }

// One diagonal, eight cells. W0..W7 = dx window value for cell 0..7
// (cell c uses window index K+7-c).
#define STEP8(K, W0, W1, W2, W3, W4, W5, W6, W7) { \
  float sh1 = dpp_shr1_inj(r1_7, INF_F); \
  float u0 = dy0 - (W0); float u1 = dy1 - (W1); \
  float u2 = dy2 - (W2); float u3 = dy3 - (W3); \
  float u4 = dy4 - (W4); float u5 = dy5 - (W5); \
  float u6 = dy6 - (W6); float u7 = dy7 - (W7); \
  float nv0 = fmaf(u0, u0, min3f(SH2,  sh1,  r1_0)); \
  float nv1 = fmaf(u1, u1, min3f(r2_0, r1_0, r1_1)); \
  float nv2 = fmaf(u2, u2, min3f(r2_1, r1_1, r1_2)); \
  float nv3 = fmaf(u3, u3, min3f(r2_2, r1_2, r1_3)); \
  float nv4 = fmaf(u4, u4, min3f(r2_3, r1_3, r1_4)); \
  float nv5 = fmaf(u5, u5, min3f(r2_4, r1_4, r1_5)); \
  float nv6 = fmaf(u6, u6, min3f(r2_5, r1_5, r1_6)); \
  float nv7 = fmaf(u7, u7, min3f(r2_6, r1_6, r1_7)); \
  if ((K) == 28) { if (cc == 31) ans = nv7; } \
  SH2 = sh1; \
  r2_0 = r1_0; r2_1 = r1_1; r2_2 = r1_2; r2_3 = r1_3; \
  r2_4 = r1_4; r2_5 = r1_5; r2_6 = r1_6; \
  r1_0 = nv0; r1_1 = nv1; r1_2 = nv2; r1_3 = nv3; \
  r1_4 = nv4; r1_5 = nv5; r1_6 = nv6; r1_7 = nv7; }

#define CHUNK(C, XU, XP) { \
  const int cc = (C); \
  PINW40(XU); \
  if (cc < 31) { LOADW40(XP, fb0 + 16 * (cc + 1)); } \
  asm volatile("" ::: "memory"); \
  STEP8(0,  XU##7,  XU##6,  XU##5,  XU##4,  XU##3,  XU##2,  XU##1,  XU##0 ) \
  STEP8(1,  XU##8,  XU##7,  XU##6,  XU##5,  XU##4,  XU##3,  XU##2,  XU##1 ) \
  STEP8(2,  XU##9,  XU##8,  XU##7,  XU##6,  XU##5,  XU##4,  XU##3,  XU##2 ) \
  STEP8(3,  XU##10, XU##9,  XU##8,  XU##7,  XU##6,  XU##5,  XU##4,  XU##3 ) \
  STEP8(4,  XU##11, XU##10, XU##9,  XU##8,  XU##7,  XU##6,  XU##5,  XU##4 ) \
  STEP8(5,  XU##12, XU##11, XU##10, XU##9,  XU##8,  XU##7,  XU##6,  XU##5 ) \
  STEP8(6,  XU##13, XU##12, XU##11, XU##10, XU##9,  XU##8,  XU##7,  XU##6 ) \
  STEP8(7,  XU##14, XU##13, XU##12, XU##11, XU##10, XU##9,  XU##8,  XU##7 ) \
  STEP8(8,  XU##15, XU##14, XU##13, XU##12, XU##11, XU##10, XU##9,  XU##8 ) \
  STEP8(9,  XU##16, XU##15, XU##14, XU##13, XU##12, XU##11, XU##10, XU##9 ) \
  STEP8(10, XU##17, XU##16, XU##15, XU##14, XU##13, XU##12, XU##11, XU##10) \
  STEP8(11, XU##18, XU##17, XU##16, XU##15, XU##14, XU##13, XU##12, XU##11) \
  STEP8(12, XU##19, XU##18, XU##17, XU##16, XU##15, XU##14, XU##13, XU##12) \
  STEP8(13, XU##20, XU##19, XU##18, XU##17, XU##16, XU##15, XU##14, XU##13) \
  STEP8(14, XU##21, XU##20, XU##19, XU##18, XU##17, XU##16, XU##15, XU##14) \
  STEP8(15, XU##22, XU##21, XU##20, XU##19, XU##18, XU##17, XU##16, XU##15) \
  STEP8(16, XU##23, XU##22, XU##21, XU##20, XU##19, XU##18, XU##17, XU##16) \
  STEP8(17, XU##24, XU##23, XU##22, XU##21, XU##20, XU##19, XU##18, XU##17) \
  STEP8(18, XU##25, XU##24, XU##23, XU##22, XU##21, XU##20, XU##19, XU##18) \
  STEP8(19, XU##26, XU##25, XU##24, XU##23, XU##22, XU##21, XU##20, XU##19) \
  STEP8(20, XU##27, XU##26, XU##25, XU##24, XU##23, XU##22, XU##21, XU##20) \
  STEP8(21, XU##28, XU##27, XU##26, XU##25, XU##24, XU##23, XU##22, XU##21) \
  STEP8(22, XU##29, XU##28, XU##27, XU##26, XU##25, XU##24, XU##23, XU##22) \
  STEP8(23, XU##30, XU##29, XU##28, XU##27, XU##26, XU##25, XU##24, XU##23) \
  STEP8(24, XU##31, XU##30, XU##29, XU##28, XU##27, XU##26, XU##25, XU##24) \
  STEP8(25, XU##32, XU##31, XU##30, XU##29, XU##28, XU##27, XU##26, XU##25) \
  STEP8(26, XU##33, XU##32, XU##31, XU##30, XU##29, XU##28, XU##27, XU##26) \
  STEP8(27, XU##34, XU##33, XU##32, XU##31, XU##30, XU##29, XU##28, XU##27) \
  STEP8(28, XU##35, XU##34, XU##33, XU##32, XU##31, XU##30, XU##29, XU##28) \
  STEP8(29, XU##36, XU##35, XU##34, XU##33, XU##32, XU##31, XU##30, XU##29) \
  STEP8(30, XU##37, XU##36, XU##35, XU##34, XU##33, XU##32, XU##31, XU##30) \
  STEP8(31, XU##38, XU##37, XU##36, XU##35, XU##34, XU##33, XU##32, XU##31) }

__global__ __launch_bounds__(64, 1)
void sdtw_kernel(const float* __restrict__ input,
                 const float* __restrict__ target,
                 float* __restrict__ out) {
  const int b = blockIdx.x;
  const int t = threadIdx.x;          // lane 0..63; rows 8t .. 8t+7

  // dx table, 4 bank-rotated replicas. dxe[r*1546 + 512 + m] = dx[m],
  // m in [0,510]; zero-padded elsewhere. 1546 mod 32 == 10 => replica r
  // shifts banks by 10r.
  __shared__ __align__(8) float dxe[4 * 1546];

  const float* __restrict__ inp = input + b * 512;
  const float* __restrict__ tgt = target + b * 512;

  for (int rr = 0; rr < 4; ++rr)
    for (int i = t; i < 1546; i += 64) {
      float v = 0.0f;
      if (i >= 512 && i <= 1022) v = inp[i - 511] - inp[i - 512];
      dxe[rr * 1546 + i] = v;
    }

  // dy for the 8 owned rows (row 8t+c uses dy index 8t+c-1)
  const int rb = 8 * t;
  float dy0 = (t == 0) ? 0.0f : tgt[rb]     - tgt[rb - 1];
  float dy1 = tgt[rb + 1] - tgt[rb];
  float dy2 = tgt[rb + 2] - tgt[rb + 1];
  float dy3 = tgt[rb + 3] - tgt[rb + 2];
  float dy4 = tgt[rb + 4] - tgt[rb + 3];
  float dy5 = tgt[rb + 5] - tgt[rb + 4];
  float dy6 = tgt[rb + 6] - tgt[rb + 5];
  float dy7 = tgt[rb + 7] - tgt[rb + 6];

  // DP state: r1_* = rows @ diag d-1, r2_* = rows 0..6 @ diag d-2,
  // SH2 = neighbor row (8t-1) @ diag d-2. Seed R[0][0]=0 rides r2_0.
  float r1_0 = INF_F, r1_1 = INF_F, r1_2 = INF_F, r1_3 = INF_F;
  float r1_4 = INF_F, r1_5 = INF_F, r1_6 = INF_F, r1_7 = INF_F;
  float r2_0 = (t == 0) ? 0.0f : INF_F;
  float r2_1 = INF_F, r2_2 = INF_F, r2_3 = INF_F;
  float r2_4 = INF_F, r2_5 = INF_F, r2_6 = INF_F;
  float SH2 = INF_F;
  float ans = INF_F;

  float xa0,xa1,xa2,xa3,xa4,xa5,xa6,xa7,xa8,xa9,xa10,xa11,xa12,xa13,xa14,xa15;
  float xa16,xa17,xa18,xa19,xa20,xa21,xa22,xa23,xa24,xa25,xa26,xa27,xa28,xa29;
  float xa30,xa31,xa32,xa33,xa34,xa35,xa36,xa37,xa38,xa39;
  float xb0,xb1,xb2,xb3,xb4,xb5,xb6,xb7,xb8,xb9,xb10,xb11,xb12,xb13,xb14,xb15;
  float xb16,xb17,xb18,xb19,xb20,xb21,xb22,xb23,xb24,xb25,xb26,xb27,xb28,xb29;
  float xb30,xb31,xb32,xb33,xb34,xb35,xb36,xb37,xb38,xb39;

  // Window base (float2 units): lane t, chunk cc reads float2
  // [fb0 + 16*cc, +20) of its replica. Float index w of the window maps
  // to dx[m], m = 32*cc - 8t - 6 + w; step k cell c uses w = k+7-c.
  const float2* dxw = ((const float2*)dxe) + 773 * ((t >> 2) & 3);
  const int fb0 = 253 - 4 * t;

  __syncthreads();                    // staging visible; only barrier

  LOADW40(xa, fb0);                   // chunk 0 window

#pragma unroll 1
  for (int c = 0; c < 32; c += 2) {
    CHUNK(c,     xa, xb)
    CHUNK(c + 1, xb, xa)
  }

  // ans captured at chunk 31, step 28 (diag 1022) from row 511 = lane63.c7
  if (t == 63) {
    atomicAdd(out, ans * (1.0f / 64.0f));
  }
}

extern "C" void kernel_launch(void* const* d_in, const int* in_sizes, int n_in,
                              void* d_out, int out_size, void* d_ws, size_t ws_size,
                              hipStream_t stream) {
  const float* input  = (const float*)d_in[0];
  const float* target = (const float*)d_in[1];
  float* out = (float*)d_out;

  hipMemsetAsync(out, 0, sizeof(float), stream);
  sdtw_kernel<<<64, 64, 0, stream>>>(input, target, out);
}

// Round 3
// 108.987 us; speedup vs baseline: 1.0110x; 1.0110x over previous
//
#include <hip/hip_runtime.h>
#include <math.h>

// Soft-DTW (DILATE, alpha=1, gamma=0.01), B=64, N=512, F=1, n=511.
// R21: single-wave-per-batch (8 rows/lane) with KCH=16 chunks.
// R19 (KCH=32) needed ~105 live VGPRs but the scheduler targets ~88 and
// sank the ds_reads into the step stream (exposed LDS latency, 133cy/diag).
// R20's pins+mem-clobber made it worse: allocator satisfied pins via AGPR
// round-trips (VGPR_Count still 88) and the clobber forced lgkmcnt(0)
// right after the load batch (171 cy/diag). R21 shrinks demand instead:
// window 40->24 floats/lane, double-buffered = 48 regs; total natural
// liveness ~80 fits the allocator's comfort zone, so the minimal-pressure
// schedule IS the prefetch schedule. Pins only at consume time (one chunk
// = ~900cy after issue); no memory clobber.
//
// Recursion per diagonal d, cell c=0..7 (row 8l+c):
//   nv[c] = (dy[c] - dx[j-1])^2 + min3(prev2[c-1], prev1[c-1], prev1[c])
// Cross-lane only for c==0 via DPP wave_shr1 of r1_7 (1 DPP / 8 rows).
// Lane 0 injects INF; R[0][0]=0 seed rides r2_0 (lane 0). Invalid cells
// stay ~INF by construction (ulp(1e9)=64 absorbs u^2; valid values <=
// ~1e5 so drifted INF never leaks into a valid min). Validated by R19/R20
// passing with absmax=0.
//
// dx window, chunk cc (16 diagonals), step k, cell c: uses window float
// index w = k+7-c (w in [0,22]); float index in replica = 512 + 16cc
// - 8t - 6 + w; kept in 24 regs (12 float2), double-buffered xa/xb.
// Per-lane float2 base fb0+8cc with fb0 = 253-4t (even-aligned, in-pad
// for all t,cc). Lane stride 32B => naive 16-way bank conflict on
// ds_read_b64; dxe replicated 4x at stride 1546 floats (+10 banks per
// replica), lane uses replica (t>>2)&3 => residual 4-way across
// {l,l+16,l+32,l+48} = wave64 b64 floor.

#define INF_F 1000000000.0f

// whole-wave shift right by 1; lane0 receives `oldv` (bound_ctrl=0 keeps old)
__device__ __forceinline__ float dpp_shr1_inj(float x, float oldv){
  int r = __builtin_amdgcn_update_dpp(__float_as_int(oldv), __float_as_int(x),
                                      0x138 /*WAVE_SHR1*/, 0xf, 0xf, false);
  return __int_as_float(r);
}
__device__ __forceinline__ float min3f(float a, float b, float c){
  float d;
  asm("v_min3_f32 %0, %1, %2, %3" : "=v"(d) : "v"(a), "v"(b), "v"(c));
  return d;
}
#define PINF(v) asm volatile("" : "+v"(v))

// load 24-float window (12 float2, even-aligned) into P##0..P##23
#define LOADW24(P, FB) { const float2* _p = dxw + (FB); \
  float2 a0=_p[0],a1=_p[1],a2=_p[2],a3=_p[3],a4=_p[4],a5=_p[5]; \
  float2 a6=_p[6],a7=_p[7],a8=_p[8],a9=_p[9],a10=_p[10],a11=_p[11]; \
  P##0=a0.x;  P##1=a0.y;  P##2=a1.x;  P##3=a1.y;  P##4=a2.x;  P##5=a2.y; \
  P##6=a3.x;  P##7=a3.y;  P##8=a4.x;  P##9=a4.y;  P##10=a5.x; P##11=a5.y; \
  P##12=a6.x; P##13=a6.y; P##14=a7.x; P##15=a7.y; P##16=a8.x; P##17=a8.y; \
  P##18=a9.x; P##19=a9.y; P##20=a10.x;P##21=a10.y;P##22=a11.x;P##23=a11.y; }

#define PINW24(P) { PINF(P##0); PINF(P##1); PINF(P##2); PINF(P##3); \
  PINF(P##4); PINF(P##5); PINF(P##6); PINF(P##7); PINF(P##8); PINF(P##9); \
  PINF(P##10); PINF(P##11); PINF(P##12); PINF(P##13); PINF(P##14); \
  PINF(P##15); PINF(P##16); PINF(P##17); PINF(P##18); PINF(P##19); \
  PINF(P##20); PINF(P##21); PINF(P##22); PINF(P##23); }

// One diagonal, eight cells. W0..W7 = dx window value for cell 0..7
// (cell c uses window index K+7-c).
#define STEP8(K, W0, W1, W2, W3, W4, W5, W6, W7) { \
  float sh1 = dpp_shr1_inj(r1_7, fINF); \
  float u0 = dy0 - (W0); float u1 = dy1 - (W1); \
  float u2 = dy2 - (W2); float u3 = dy3 - (W3); \
  float u4 = dy4 - (W4); float u5 = dy5 - (W5); \
  float u6 = dy6 - (W6); float u7 = dy7 - (W7); \
  float nv0 = fmaf(u0, u0, min3f(SH2,  sh1,  r1_0)); \
  float nv1 = fmaf(u1, u1, min3f(r2_0, r1_0, r1_1)); \
  float nv2 = fmaf(u2, u2, min3f(r2_1, r1_1, r1_2)); \
  float nv3 = fmaf(u3, u3, min3f(r2_2, r1_2, r1_3)); \
  float nv4 = fmaf(u4, u4, min3f(r2_3, r1_3, r1_4)); \
  float nv5 = fmaf(u5, u5, min3f(r2_4, r1_4, r1_5)); \
  float nv6 = fmaf(u6, u6, min3f(r2_5, r1_5, r1_6)); \
  float nv7 = fmaf(u7, u7, min3f(r2_6, r1_6, r1_7)); \
  if ((K) == 12) { if (cc == 63) ans = nv7; } \
  SH2 = sh1; \
  r2_0 = r1_0; r2_1 = r1_1; r2_2 = r1_2; r2_3 = r1_3; \
  r2_4 = r1_4; r2_5 = r1_5; r2_6 = r1_6; \
  r1_0 = nv0; r1_1 = nv1; r1_2 = nv2; r1_3 = nv3; \
  r1_4 = nv4; r1_5 = nv5; r1_6 = nv6; r1_7 = nv7; }

#define CHUNK(C, XU, XP) { \
  const int cc = (C); \
  PINW24(XU); \
  if (cc < 63) { LOADW24(XP, fb0 + 8 * (cc + 1)); } \
  STEP8(0,  XU##7,  XU##6,  XU##5,  XU##4,  XU##3,  XU##2,  XU##1,  XU##0 ) \
  STEP8(1,  XU##8,  XU##7,  XU##6,  XU##5,  XU##4,  XU##3,  XU##2,  XU##1 ) \
  STEP8(2,  XU##9,  XU##8,  XU##7,  XU##6,  XU##5,  XU##4,  XU##3,  XU##2 ) \
  STEP8(3,  XU##10, XU##9,  XU##8,  XU##7,  XU##6,  XU##5,  XU##4,  XU##3 ) \
  STEP8(4,  XU##11, XU##10, XU##9,  XU##8,  XU##7,  XU##6,  XU##5,  XU##4 ) \
  STEP8(5,  XU##12, XU##11, XU##10, XU##9,  XU##8,  XU##7,  XU##6,  XU##5 ) \
  STEP8(6,  XU##13, XU##12, XU##11, XU##10, XU##9,  XU##8,  XU##7,  XU##6 ) \
  STEP8(7,  XU##14, XU##13, XU##12, XU##11, XU##10, XU##9,  XU##8,  XU##7 ) \
  STEP8(8,  XU##15, XU##14, XU##13, XU##12, XU##11, XU##10, XU##9,  XU##8 ) \
  STEP8(9,  XU##16, XU##15, XU##14, XU##13, XU##12, XU##11, XU##10, XU##9 ) \
  STEP8(10, XU##17, XU##16, XU##15, XU##14, XU##13, XU##12, XU##11, XU##10) \
  STEP8(11, XU##18, XU##17, XU##16, XU##15, XU##14, XU##13, XU##12, XU##11) \
  STEP8(12, XU##19, XU##18, XU##17, XU##16, XU##15, XU##14, XU##13, XU##12) \
  STEP8(13, XU##20, XU##19, XU##18, XU##17, XU##16, XU##15, XU##14, XU##13) \
  STEP8(14, XU##21, XU##20, XU##19, XU##18, XU##17, XU##16, XU##15, XU##14) \
  STEP8(15, XU##22, XU##21, XU##20, XU##19, XU##18, XU##17, XU##16, XU##15) }

__global__ __launch_bounds__(64, 1)
void sdtw_kernel(const float* __restrict__ input,
                 const float* __restrict__ target,
                 float* __restrict__ out) {
  const int b = blockIdx.x;
  const int t = threadIdx.x;          // lane 0..63; rows 8t .. 8t+7

  // dx table, 4 bank-rotated replicas. dxe[r*1546 + 512 + m] = dx[m],
  // m in [0,510]; zero-padded elsewhere. 1546 mod 32 == 10 => replica r
  // shifts banks by 10r.
  __shared__ __align__(8) float dxe[4 * 1546];
  __shared__ float tg[512];

  const float* __restrict__ inp = input + b * 512;
  const float* __restrict__ tgt = target + b * 512;

  for (int i = t; i < 1546; i += 64) {
    float v = 0.0f;
    if (i >= 512 && i <= 1022) v = inp[i - 511] - inp[i - 512];
    dxe[i] = v; dxe[1546 + i] = v; dxe[3092 + i] = v; dxe[4638 + i] = v;
  }
  for (int i = t; i < 512; i += 64) tg[i] = tgt[i];

  __syncthreads();                    // staging visible; only barrier

  // dy for the 8 owned rows (row 8t+c uses dy index 8t+c-1), from LDS
  const int rb = 8 * t;
  float dy0 = (t == 0) ? 0.0f : tg[rb]     - tg[rb - 1];
  float dy1 = tg[rb + 1] - tg[rb];
  float dy2 = tg[rb + 2] - tg[rb + 1];
  float dy3 = tg[rb + 3] - tg[rb + 2];
  float dy4 = tg[rb + 4] - tg[rb + 3];
  float dy5 = tg[rb + 5] - tg[rb + 4];
  float dy6 = tg[rb + 6] - tg[rb + 5];
  float dy7 = tg[rb + 7] - tg[rb + 6];

  // DP state: r1_* = rows @ diag d-1, r2_* = rows 0..6 @ diag d-2,
  // SH2 = neighbor row (8t-1) @ diag d-2. Seed R[0][0]=0 rides r2_0.
  float r1_0 = INF_F, r1_1 = INF_F, r1_2 = INF_F, r1_3 = INF_F;
  float r1_4 = INF_F, r1_5 = INF_F, r1_6 = INF_F, r1_7 = INF_F;
  float r2_0 = (t == 0) ? 0.0f : INF_F;
  float r2_1 = INF_F, r2_2 = INF_F, r2_3 = INF_F;
  float r2_4 = INF_F, r2_5 = INF_F, r2_6 = INF_F;
  float SH2 = INF_F;
  float ans = INF_F;
  const float fINF = INF_F;           // materialized once; DPP inject value

  float xa0,xa1,xa2,xa3,xa4,xa5,xa6,xa7,xa8,xa9,xa10,xa11;
  float xa12,xa13,xa14,xa15,xa16,xa17,xa18,xa19,xa20,xa21,xa22,xa23;
  float xb0,xb1,xb2,xb3,xb4,xb5,xb6,xb7,xb8,xb9,xb10,xb11;
  float xb12,xb13,xb14,xb15,xb16,xb17,xb18,xb19,xb20,xb21,xb22,xb23;

  // Window base (float2 units): lane t, chunk cc reads float2
  // [fb0 + 8*cc, +12) of its replica. Float index w of the window maps
  // to dx[m], m = 16*cc - 8t - 6 + w; step k cell c uses w = k+7-c.
  const float2* dxw = ((const float2*)dxe) + 773 * ((t >> 2) & 3);
  const int fb0 = 253 - 4 * t;

  LOADW24(xa, fb0);                   // chunk 0 window

#pragma unroll 1
  for (int c = 0; c < 64; c += 2) {
    CHUNK(c,     xa, xb)
    CHUNK(c + 1, xb, xa)
  }

  // ans captured at chunk 63, step 12 (diag 1022) from row 511 = lane63.c7
  if (t == 63) {
    atomicAdd(out, ans * (1.0f / 64.0f));
  }
}

extern "C" void kernel_launch(void* const* d_in, const int* in_sizes, int n_in,
                              void* d_out, int out_size, void* d_ws, size_t ws_size,
                              hipStream_t stream) {
  const float* input  = (const float*)d_in[0];
  const float* target = (const float*)d_in[1];
  float* out = (float*)d_out;

  hipMemsetAsync(out, 0, sizeof(float), stream);
  sdtw_kernel<<<64, 64, 0, stream>>>(input, target, out);
}

// Round 5
// 105.813 us; speedup vs baseline: 1.0414x; 1.0300x over previous
//
#include <hip/hip_runtime.h>
#include <math.h>

// Soft-DTW (DILATE, alpha=1, gamma=0.01), B=64, N=512, F=1, n=511.
// R23 = R22 with the token-paste compile fix ((QU##0).y instead of
// QU##0.y -- '2.x' lexes as one pp-number so IU##2.x is an invalid paste).
//
// 8-wave pipeline, 1 row/lane. Evidence R19-R21: a solo wave issues at
// ~5.1 cy/instr (133 cy/diag for 26 VALU, zero residual) -> per-batch
// latency = instr/diag spread over SIMDs * cadence. R21 (1 SIMD) = 57us;
// R18 (4 SIMDs, 2 rows/lane, ~9 instr/step) = ~32us. R23 spreads a
// diagonal over 8 waves (2/SIMD so cadence gaps are co-issued away) at
// 4 VALU/step/wave: sh1=DPP(r1), u=dy-x, mn=min3(SH2,sh1,r1),
// nv=fma(u,u,mn). With 1 row/lane the recursion needs NO own-row d-2
// state (R[i-1][j-1],R[i-1][j] come from the neighbor via SH2/sh1;
// R[i][j-1] is r1).
//
// dx delivery: DPP conveyor. m(t,k+1) = m(t-1,k), so next step's dx is
// wave_shr1 of the current with a lane-0 inject of dx[8cc+k+2-64w] --
// a WAVE-UNIFORM value, loaded per chunk as 4 broadcast b64 (conflict-
// free). No per-lane window loads at all -> 8 waves don't saturate the
// LDS pipe (only uniform broadcasts + lane63 mailbox writes).
//
// Wave w owns rows ri = 64w + t. Chunk = 8 diagonals (s = 8cc+k,
// d = s+2). Wave w+1's lane0 neighbor values come from wave w's lane63
// r1 history via LDS mailbox Mbx[w][idx = s'+2], batched per chunk,
// acquire/release + s_sleep poll (R18-proven). Consumer chunk cc uses
// idx 8cc+1..8cc+8 (5 uniform b64); producer writes idx 8cc+2..8cc+9
// (4 b64, lane63). Slots idx 0,1 stay INF (prefill). Double-buffered
// prefetch polls flag >= cc+2 AFTER chunk cc's steps.
//
// Seed: R[0][0]=0 enters as SH2 init of (w0,lane1); row 0 stays ~INF.
// Invalid cells hold ~INF by construction (ulp(1e9)=64 absorbs u^2
// increments; valid path values << 1e9) -- R19/R21-proven (absmax=0).

#define INF_F 1000000000.0f

// whole-wave shift toward higher lanes; lane0 receives `oldv`
// (bound_ctrl=0 keeps old in invalid lane). 0x138 empirically:
// result[i] = src[i-1], lane0 invalid (R18/R21-proven direction).
__device__ __forceinline__ float dpp_shr1_inj(float x, float oldv){
  int r = __builtin_amdgcn_update_dpp(__float_as_int(oldv), __float_as_int(x),
                                      0x138, 0xf, 0xf, false);
  return __int_as_float(r);
}
__device__ __forceinline__ float min3f(float a, float b, float c){
  float d;
  asm("v_min3_f32 %0, %1, %2, %3" : "=v"(d) : "v"(a), "v"(b), "v"(c));
  return d;
}
#define PINF2(v) asm volatile("" : "+v"(v.x), "+v"(v.y))
#define PINQ(P) { PINF2(P##0); PINF2(P##1); PINF2(P##2); PINF2(P##3); PINF2(P##4); }
#define PINI(P) { PINF2(P##0); PINF2(P##1); PINF2(P##2); PINF2(P##3); }

// One diagonal step. QV = mailbox inject (neighbor row @ d-1, lane0 only
// matters), IV = conveyor inject (dx stream, lane0 only matters).
#define STEP(K, QV, IV) { \
  float sh1 = dpp_shr1_inj(r1, (QV)); \
  float u   = dy - x; \
  float mn  = min3f(SH2, sh1, r1); \
  float nv  = fmaf(u, u, mn); \
  pb##K = nv; \
  if ((K) == 4) { if (cc == 127) ans = nv; } \
  x = dpp_shr1_inj(x, (IV)); \
  SH2 = sh1; r1 = nv; }

#define CHUNK(C, QU, IU, QP, IP) { \
  const int cc = (C); \
  PINQ(QU); PINI(IU); \
  STEP(0, (QU##0).y, (IU##0).x) \
  STEP(1, (QU##1).x, (IU##0).y) \
  STEP(2, (QU##1).y, (IU##1).x) \
  STEP(3, (QU##2).x, (IU##1).y) \
  STEP(4, (QU##2).y, (IU##2).x) \
  STEP(5, (QU##3).x, (IU##2).y) \
  STEP(6, (QU##3).y, (IU##3).x) \
  STEP(7, (QU##4).x, (IU##3).y) \
  if (w < 7) { \
    if (t == 63) { \
      float2* pd = (float2*)&Mbx[w][8*cc + 2]; \
      pd[0] = make_float2(pb0, pb1); pd[1] = make_float2(pb2, pb3); \
      pd[2] = make_float2(pb4, pb5); pd[3] = make_float2(pb6, pb7); \
    } \
    __hip_atomic_store(&flagz[w], cc + 1, __ATOMIC_RELEASE, \
                       __HIP_MEMORY_SCOPE_WORKGROUP); \
  } \
  if (cc < 127) { \
    { const float2* ip2 = mdx2 + (ibase + 4*(cc+1)); \
      IP##0 = ip2[0]; IP##1 = ip2[1]; IP##2 = ip2[2]; IP##3 = ip2[3]; } \
    if (w > 0) { \
      while (__hip_atomic_load(&flagz[w-1], __ATOMIC_ACQUIRE, \
                               __HIP_MEMORY_SCOPE_WORKGROUP) <= cc + 1) { \
        __builtin_amdgcn_s_sleep(1); \
      } \
      const float2* qp2 = mbr2 + 4*(cc+1); \
      QP##0 = qp2[0]; QP##1 = qp2[1]; QP##2 = qp2[2]; \
      QP##3 = qp2[3]; QP##4 = qp2[4]; \
    } \
  } }

__global__ __launch_bounds__(512, 1)
void sdtw_kernel(const float* __restrict__ input,
                 const float* __restrict__ target,
                 float* __restrict__ out) {
  const int b   = blockIdx.x;
  const int tid = threadIdx.x;
  const int w   = tid >> 6;           // wave 0..7 (pipeline stage)
  const int t   = tid & 63;           // lane
  const int ri  = (w << 6) + t;       // owned row 0..511

  // dxpad table: Mdx[512 + f] = dx[f] for f in [0,510], else 0.
  __shared__ __align__(8) float Mdx[1544];
  // Mailbox: Mbx[wi][idx] = wave wi's producer r1 after abs step s'=idx-2.
  __shared__ __align__(8) float Mbx[7][1028];
  __shared__ int flagz[7];

  const float* __restrict__ inp = input + b * 512;
  const float* __restrict__ tgt = target + b * 512;

  for (int i = tid; i < 1544; i += 512) {
    int f = i - 512;
    float v = 0.0f;
    if (f >= 0 && f <= 510) v = inp[f + 1] - inp[f];
    Mdx[i] = v;
  }
  for (int i = tid; i < 7 * 1028; i += 512) (&Mbx[0][0])[i] = INF_F;
  if (tid < 7) flagz[tid] = 0;

  // dy for owned row (row ri uses dy index ri-1); row 0 is boundary junk
  float dy = (ri >= 1) ? (tgt[ri] - tgt[ri - 1]) : 0.0f;

  float r1  = INF_F;                       // own row @ diag d-1
  float SH2 = (ri == 1) ? 0.0f : INF_F;    // neighbor row @ diag d-2 (seed)
  float ans = INF_F;
  const float fINF = INF_F;

  float2 qa0,qa1,qa2,qa3,qa4, qb0,qb1,qb2,qb3,qb4;   // mailbox regs
  float2 ia0,ia1,ia2,ia3, ib0,ib1,ib2,ib3;           // conveyor inject regs
  qa0 = make_float2(fINF,fINF); qa1=qa0; qa2=qa0; qa3=qa0; qa4=qa0;
  qb0 = qa0; qb1=qa0; qb2=qa0; qb3=qa0; qb4=qa0;
  ib0 = make_float2(0.f,0.f); ib1=ib0; ib2=ib0; ib3=ib0;
  float pb0,pb1,pb2,pb3,pb4,pb5,pb6,pb7;

  __syncthreads();                    // staging visible; only barrier

  // conveyor init: x = dx[m], m = 1 - ri  (chunk 0, step 0)
  float x = Mdx[513 - ri];

  const float2* mdx2 = (const float2*)Mdx;
  const int ibase = 257 - 32 * w;     // float2 idx of Mdx[514 - 64w]
  const float2* mbr2 = (const float2*)&Mbx[(w > 0) ? (w - 1) : 0][0];

  // chunk 0 inject regs
  { const float2* ip2 = mdx2 + ibase;
    ia0 = ip2[0]; ia1 = ip2[1]; ia2 = ip2[2]; ia3 = ip2[3]; }
  // chunk 0 mailbox regs (consumer waits for producer's chunk 0)
  if (w > 0) {
    while (__hip_atomic_load(&flagz[w-1], __ATOMIC_ACQUIRE,
                             __HIP_MEMORY_SCOPE_WORKGROUP) <= 0) {
      __builtin_amdgcn_s_sleep(1);
    }
    qa0 = mbr2[0]; qa1 = mbr2[1]; qa2 = mbr2[2]; qa3 = mbr2[3]; qa4 = mbr2[4];
  }

#pragma unroll 1
  for (int c = 0; c < 128; c += 2) {
    CHUNK(c,     qa, ia, qb, ib)
    CHUNK(c + 1, qb, ib, qa, ia)
  }

  // ans captured at cc=127, K=4 (abs step 1020, diag 1022) on row 511
  if (w == 7 && t == 63) {
    atomicAdd(out, ans * (1.0f / 64.0f));
  }
}

extern "C" void kernel_launch(void* const* d_in, const int* in_sizes, int n_in,
                              void* d_out, int out_size, void* d_ws, size_t ws_size,
                              hipStream_t stream) {
  const float* input  = (const float*)d_in[0];
  const float* target = (const float*)d_in[1];
  float* out = (float*)d_out;

  hipMemsetAsync(out, 0, sizeof(float), stream);
  sdtw_kernel<<<64, 512, 0, stream>>>(input, target, out);
}

// Round 6
// 99.025 us; speedup vs baseline: 1.1127x; 1.0686x over previous
//
#include <hip/hip_runtime.h>
#include <math.h>

// Soft-DTW (DILATE, alpha=1, gamma=0.01), B=64, N=512, F=1, n=511.
// R24 = R18 geometry (4 waves, 2 rows/lane, proven at ~32us dispatch) +
// de-serialized handoff. Model from R18/R21/R23: per-wave issue cadence
// ~5.1 cy/instr; R23's 8-wave variant died on the CU-shared LDS pipe
// (120 LDS ops per chunk period ~= 720cy) + blocking poll chains. R18's
// 64cy/step = ~10 instr x 5cy + ~15cy serialized handoff (poll, q-loads
// and release drain adjacent to use). R24 removes the serial part:
//  - chunk-top prefetch: at top of chunk cc, ensure producer finished
//    chunk cc+1 (flag >= cc+2), then issue q-loads + window loads for
//    cc+1; they fly under chunk cc's 8 steps (~280cy) and are pinned at
//    the NEXT chunk top. Release-store's lgkmcnt drain hits completed
//    loads.
//  - non-blocking flag check: fcur sampled via relaxed load one chunk
//    early; chunk-top does a register compare (fast path); blocking
//    acquire poll + s_sleep only as fallback. Steady state: lag ~3
//    chunks per interface, zero blocking.
// KCH=8 (128 chunks): regs ~70 (xa/xb 10+10, qa/qb 10+10, DP state 4,
// dy 2, pb 8, misc) -- inside the allocator comfort zone (R21 lesson).
//
// Recursion per step s (d=s+2), thread t owns rows 2t (lo), 2t+1 (hi):
//   nv_hi = (dy_hi - dx[s-2t])^2   + min3(r2_lo, r1_lo, r1_hi)
//   nv_lo = (dy_lo - dx[s+1-2t])^2 + min3(SH2,  sh1,  r1_lo)
// sh1 = DPP wave_shr1 of r1_hi with lane0 := mailbox M[s-1] (producer
// lane63's nv_hi at step s-1); SH2 carries M[s-2]. Seed R[0][0]=0 rides
// r2_lo of t==0. Invalid cells hold ~INF by construction (R0/R21/R23
// proven, absmax=0).
//
// Mailbox: Mbx[I][idx=sigma+2] = wave I lane63 nv_hi after step sigma.
// Producer chunk cc writes idx 8cc+2..8cc+9 (4 f2); consumer chunk cc
// injects idx 8cc+1..8cc+8 (5 f2 from idx 8cc..8cc+9, q0.y..q4.x).
// Prefill idx 0,1 = INF. flag[I] = chunks completed by wave I.
// Window: Mdx[512+f]=dx[f] (f in [0,510], pad 0). Chunk cc loads 5 f2
// at f2-idx 256+4cc-t (floats F..F+9, F=512+8cc-2t); XHI(k)=win[k],
// XLO(k)=win[k+1].

#define INF_F 1000000000.0f

// whole-wave shift toward higher lanes; lane0 receives `oldv`
__device__ __forceinline__ float dpp_shr1_inj(float x, float oldv){
  int r = __builtin_amdgcn_update_dpp(__float_as_int(oldv), __float_as_int(x),
                                      0x138 /*WAVE_SHR1*/, 0xf, 0xf, false);
  return __int_as_float(r);
}
__device__ __forceinline__ float min3f(float a, float b, float c){
  float d;
  asm("v_min3_f32 %0, %1, %2, %3" : "=v"(d) : "v"(a), "v"(b), "v"(c));
  return d;
}
#define PINF(v) asm volatile("" : "+v"(v))
#define PINF2(v) asm volatile("" : "+v"(v.x), "+v"(v.y))

#define PINW(P) { PINF(P##0); PINF(P##1); PINF(P##2); PINF(P##3); PINF(P##4); \
  PINF(P##5); PINF(P##6); PINF(P##7); PINF(P##8); PINF(P##9); }
#define PINQ(P) { PINF2(P##0); PINF2(P##1); PINF2(P##2); PINF2(P##3); PINF2(P##4); }

// One diagonal, two cells (R0-proven core). MB rides DPP lane0 inject.
#define STEP2(K, MB, XLO, XHI) { \
  float sh1 = dpp_shr1_inj(r1_hi, (MB)); \
  float uL  = dy_lo - (XLO); \
  float uH  = dy_hi - (XHI); \
  float nv_hi = fmaf(uH, uH, min3f(r2_lo, r1_lo, r1_hi)); \
  float nv_lo = fmaf(uL, uL, min3f(SH2, sh1, r1_lo)); \
  pb##K = nv_hi; \
  if ((K) == 4) { if (cc == 127) ans = nv_hi; } \
  SH2 = sh1; r2_lo = r1_lo; r1_lo = nv_lo; r1_hi = nv_hi; }

#define CHUNK(C, XU, QU, XP, QP) { \
  const int cc = (C); \
  if (cc < 127) { \
    if (w > 0) { \
      if (fcur < cc + 2) { \
        do { __builtin_amdgcn_s_sleep(1); \
             fcur = __hip_atomic_load(&flagz[w-1], __ATOMIC_ACQUIRE, \
                                      __HIP_MEMORY_SCOPE_WORKGROUP); \
        } while (fcur < cc + 2); \
      } \
      asm volatile("" ::: "memory"); \
      { const float2* qp2 = mbr2 + 4*(cc+1); \
        QP##0 = qp2[0]; QP##1 = qp2[1]; QP##2 = qp2[2]; \
        QP##3 = qp2[3]; QP##4 = qp2[4]; } \
      fcur = __hip_atomic_load(&flagz[w-1], __ATOMIC_RELAXED, \
                               __HIP_MEMORY_SCOPE_WORKGROUP); \
    } \
    { const float2* ip2 = wbase2 + 4*(cc+1); \
      float2 a0=ip2[0],a1=ip2[1],a2=ip2[2],a3=ip2[3],a4=ip2[4]; \
      XP##0=a0.x; XP##1=a0.y; XP##2=a1.x; XP##3=a1.y; XP##4=a2.x; \
      XP##5=a2.y; XP##6=a3.x; XP##7=a3.y; XP##8=a4.x; XP##9=a4.y; } \
    asm volatile("" ::: "memory"); \
  } \
  PINW(XU); PINQ(QU); \
  STEP2(0, (QU##0).y, XU##1, XU##0) \
  STEP2(1, (QU##1).x, XU##2, XU##1) \
  STEP2(2, (QU##1).y, XU##3, XU##2) \
  STEP2(3, (QU##2).x, XU##4, XU##3) \
  STEP2(4, (QU##2).y, XU##5, XU##4) \
  STEP2(5, (QU##3).x, XU##6, XU##5) \
  STEP2(6, (QU##3).y, XU##7, XU##6) \
  STEP2(7, (QU##4).x, XU##8, XU##7) \
  if (w < 3) { \
    if (t == 63) { \
      float2* pd = (float2*)&Mbx[w][8*cc + 2]; \
      pd[0] = make_float2(pb0, pb1); pd[1] = make_float2(pb2, pb3); \
      pd[2] = make_float2(pb4, pb5); pd[3] = make_float2(pb6, pb7); \
    } \
    __hip_atomic_store(&flagz[w], cc + 1, __ATOMIC_RELEASE, \
                       __HIP_MEMORY_SCOPE_WORKGROUP); \
  } }

__global__ __launch_bounds__(256, 1)
void sdtw_kernel(const float* __restrict__ input,
                 const float* __restrict__ target,
                 float* __restrict__ out) {
  const int b   = blockIdx.x;
  const int tid = threadIdx.x;        // 0..255; rows 2*tid, 2*tid+1
  const int t   = tid & 63;           // lane
  const int w   = tid >> 6;           // wave 0..3

  // Mdx[512+f] = dx[f] for f in [0,510]; zero pad elsewhere.
  __shared__ __align__(8) float Mdx[1544];
  // Mbx[I][idx] = wave I lane63 nv_hi after step idx-2. flag[I] = chunks done.
  __shared__ __align__(8) float Mbx[3][1028];
  __shared__ int flagz[3];

  const float* __restrict__ inp = input + b * 512;
  const float* __restrict__ tgt = target + b * 512;

  for (int i = tid; i < 1544; i += 256) {
    float v = 0.0f;
    if (i >= 512 && i <= 1022) v = inp[i - 511] - inp[i - 512];
    Mdx[i] = v;
  }
  if (tid < 3) flagz[tid] = 0;
  if (tid < 6) Mbx[tid >> 1][tid & 1] = INF_F;   // prefill idx 0,1 per interface

  // dy for the two owned rows (row i uses dy[i-1] = tgt[i]-tgt[i-1])
  float dy_lo = (tid >= 1) ? (tgt[2*tid] - tgt[2*tid - 1]) : 0.0f;
  float dy_hi = tgt[2*tid + 1] - tgt[2*tid];

  // DP state @ chunk 0: r1 = diag d-1 (INF), r2_lo carries R[0][0]=0 seed.
  float r1_lo = INF_F, r1_hi = INF_F;
  float r2_lo = (tid == 0) ? 0.0f : INF_F;
  float SH2   = INF_F;
  float ans   = INF_F;
  const float fINF = INF_F;
  int fcur = 0;

  float xa0,xa1,xa2,xa3,xa4,xa5,xa6,xa7,xa8,xa9;
  float xb0,xb1,xb2,xb3,xb4,xb5,xb6,xb7,xb8,xb9;
  float2 qa0,qa1,qa2,qa3,qa4, qb0,qb1,qb2,qb3,qb4;
  qa0 = make_float2(fINF, fINF); qa1=qa0; qa2=qa0; qa3=qa0; qa4=qa0;
  qb0 = qa0; qb1=qa0; qb2=qa0; qb3=qa0; qb4=qa0;
  float pb0,pb1,pb2,pb3,pb4,pb5,pb6,pb7;

  const float2* wbase2 = ((const float2*)Mdx) + (256 - tid);
  const float2* mbr2   = (const float2*)&Mbx[(w > 0) ? (w - 1) : 0][0];

  __syncthreads();                    // staging + flag init visible

  // chunk-0 window
  { const float2* ip2 = wbase2;
    float2 a0=ip2[0],a1=ip2[1],a2=ip2[2],a3=ip2[3],a4=ip2[4];
    xa0=a0.x; xa1=a0.y; xa2=a1.x; xa3=a1.y; xa4=a2.x;
    xa5=a2.y; xa6=a3.x; xa7=a3.y; xa8=a4.x; xa9=a4.y; }
  // chunk-0 mailbox regs: wait for producer chunk 0, then sample flag
  if (w > 0) {
    do { __builtin_amdgcn_s_sleep(1);
         fcur = __hip_atomic_load(&flagz[w-1], __ATOMIC_ACQUIRE,
                                  __HIP_MEMORY_SCOPE_WORKGROUP);
    } while (fcur < 1);
    qa0 = mbr2[0]; qa1 = mbr2[1]; qa2 = mbr2[2]; qa3 = mbr2[3]; qa4 = mbr2[4];
  }

#pragma unroll 1
  for (int c = 0; c < 128; c += 2) {
    CHUNK(c,     xa, qa, xb, qb)
    CHUNK(c + 1, xb, qb, xa, qa)
  }

  // ans captured at cc=127, K=4 (step 1020, diag 1022) on row 511 = tid 255 hi
  if (tid == 255) {
    atomicAdd(out, ans * (1.0f / 64.0f));
  }
}

extern "C" void kernel_launch(void* const* d_in, const int* in_sizes, int n_in,
                              void* d_out, int out_size, void* d_ws, size_t ws_size,
                              hipStream_t stream) {
  const float* input  = (const float*)d_in[0];
  const float* target = (const float*)d_in[1];
  float* out = (float*)d_out;

  hipMemsetAsync(out, 0, sizeof(float), stream);
  sdtw_kernel<<<64, 256, 0, stream>>>(input, target, out);
}

// Round 7
// 88.485 us; speedup vs baseline: 1.2453x; 1.1191x over previous
//
#include <hip/hip_runtime.h>
#include <math.h>

// Soft-DTW (DILATE, alpha=1, gamma=0.01), B=64, N=512, F=1, n=511.
// R25: 4 waves x 2 rows/lane (R18/R24 geometry), KCH=16, and the mailbox
// delivered via a LANE CONVEYOR instead of broadcast registers.
//
// Key insight: only lane 0 consumes the mailbox inject (it rides the DPP
// `old` operand of the wave_shr1). So per chunk we load ONE b32/lane:
// lane l <- Mbx[I][16cc+1+l]. Each step shifts this register one lane
// toward lane0 (WAVE_SHL1); the wave_shr1's old=qc then has
// old[lane0] = Mbx[16cc+1+k] at step k -- exactly M[s-1] for the c==0
// cell (bound_ctrl=0 keeps old's per-lane value in invalid lanes).
// Cost: +1 DPP/step, -34 registers, -8 LDS loads/chunk vs broadcast.
// Register demand ~68 (window 36 dbuf + qc 2 + pb 16 + state ~14): inside
// the allocator's clean zone (R21 evidence: 88 regs, zero exposure) so
// prefetched loads stay hoisted -- no sinking (R19), no AGPR games (R24,
// VGPR=36), no load-site pins (R20's forced-waitcnt mistake).
//
// Handoff: lag-3 fast path. At top of chunk cc, prefetch chunk cc+1's
// window (9 ds_read_b64, static dx) and q-conveyor (1 b32, needs
// flag >= cc+2). fcur was sampled one chunk earlier (relaxed); blocking
// sleep-poll only when fcur is short. Blocking inserts delay -> producer
// lead grows and never shrinks (mailbox is full-length, no backpressure)
// -> steady state: zero blocking, waves free-run at own issue rate
// (~152 instr/chunk x ~5cy = ~775cy/chunk).
//
// Recursion per step s (d=s+2), thread tid owns rows 2tid (lo), 2tid+1 (hi):
//   nv_hi = (dy_hi - dx[s-2tid])^2   + min3(r2_lo, r1_lo, r1_hi)
//   nv_lo = (dy_lo - dx[s+1-2tid])^2 + min3(SH2,  sh1,  r1_lo)
// sh1 = wave_shr1(r1_hi) with lane0 := M[s-1] via conveyor old-operand.
// Seed R[0][0]=0 rides r2_lo of tid==0. Invalid cells hold ~INF by
// construction (ulp(1e9)=64 absorbs u^2; R21/R23/R24-proven, absmax=0).
//
// Mailbox: Mbx[I][idx=sigma+2] = wave I lane63 nv_hi after step sigma.
// Producer chunk cc writes idx 16cc+2..16cc+17 (8 f2). Consumer chunk cc
// conveyor-consumes idx 16cc+1..16cc+16 (init lanes 0..15; lanes 16+ of
// the conveyor load are junk and never reach lane0 within 16 shifts).
// Prefill idx 0,1 = INF. Window: Mdx[512+f]=dx[f] (f in [0,510], pad 0);
// chunk cc loads 9 f2 at f2-idx 256-tid+8cc (floats F..F+17,
// F=512+16cc-2tid); XHI(k)=win[k], XLO(k)=win[k+1]. Lane f2 stride 8B ->
// 2-way bank aliasing on b64 = free (R24: 0 conflicts).

#define INF_F 1000000000.0f

// wave shift toward higher lanes; lane0 keeps old[lane0] (bound_ctrl=0)
__device__ __forceinline__ float dpp_shr1_old(float x, float oldv){
  int r = __builtin_amdgcn_update_dpp(__float_as_int(oldv), __float_as_int(x),
                                      0x138 /*WAVE_SHR1*/, 0xf, 0xf, false);
  return __int_as_float(r);
}
// wave shift toward lower lanes; lane63 keeps old (junk-tolerant)
__device__ __forceinline__ float dpp_shl1(float x){
  int r = __builtin_amdgcn_update_dpp(__float_as_int(x), __float_as_int(x),
                                      0x130 /*WAVE_SHL1*/, 0xf, 0xf, false);
  return __int_as_float(r);
}
__device__ __forceinline__ float min3f(float a, float b, float c){
  float d;
  asm("v_min3_f32 %0, %1, %2, %3" : "=v"(d) : "v"(a), "v"(b), "v"(c));
  return d;
}
#define PINF(v) asm volatile("" : "+v"(v))
#define PINW18(P) { PINF(P##0); PINF(P##1); PINF(P##2); PINF(P##3); \
  PINF(P##4); PINF(P##5); PINF(P##6); PINF(P##7); PINF(P##8); PINF(P##9); \
  PINF(P##10); PINF(P##11); PINF(P##12); PINF(P##13); PINF(P##14); \
  PINF(P##15); PINF(P##16); PINF(P##17); }

// One diagonal, two cells. QC = conveyor register (lane0 = M[s-1] inject).
#define STEP2(K, QC, XLO, XHI) { \
  float sh1 = dpp_shr1_old(r1_hi, (QC)); \
  (QC) = dpp_shl1((QC)); \
  float uL  = dy_lo - (XLO); \
  float uH  = dy_hi - (XHI); \
  float nv_hi = fmaf(uH, uH, min3f(r2_lo, r1_lo, r1_hi)); \
  float nv_lo = fmaf(uL, uL, min3f(SH2, sh1, r1_lo)); \
  pb##K = nv_hi; \
  if ((K) == 12) { if (cc == 63) ans = nv_hi; } \
  SH2 = sh1; r2_lo = r1_lo; r1_lo = nv_lo; r1_hi = nv_hi; }

#define CHUNK(C, XU, QCU, XP, QCP) { \
  const int cc = (C); \
  if (cc < 63) { \
    { const float2* ip2 = wbase2 + 8 * (cc + 1); \
      float2 a0=ip2[0],a1=ip2[1],a2=ip2[2],a3=ip2[3],a4=ip2[4]; \
      float2 a5=ip2[5],a6=ip2[6],a7=ip2[7],a8=ip2[8]; \
      XP##0=a0.x;  XP##1=a0.y;  XP##2=a1.x;  XP##3=a1.y;  XP##4=a2.x; \
      XP##5=a2.y;  XP##6=a3.x;  XP##7=a3.y;  XP##8=a4.x;  XP##9=a4.y; \
      XP##10=a5.x; XP##11=a5.y; XP##12=a6.x; XP##13=a6.y; XP##14=a7.x; \
      XP##15=a7.y; XP##16=a8.x; XP##17=a8.y; } \
    if (w > 0) { \
      if (fcur < cc + 2) { \
        do { __builtin_amdgcn_s_sleep(1); \
             fcur = __hip_atomic_load(&flagz[w-1], __ATOMIC_ACQUIRE, \
                                      __HIP_MEMORY_SCOPE_WORKGROUP); \
        } while (fcur < cc + 2); \
      } \
      asm volatile("" ::: "memory"); \
      QCP = qb_base[16 * (cc + 1)]; \
      fcur = __hip_atomic_load(&flagz[w-1], __ATOMIC_RELAXED, \
                               __HIP_MEMORY_SCOPE_WORKGROUP); \
    } \
  } \
  PINW18(XU); PINF(QCU); \
  STEP2(0,  QCU, XU##1,  XU##0 ) \
  STEP2(1,  QCU, XU##2,  XU##1 ) \
  STEP2(2,  QCU, XU##3,  XU##2 ) \
  STEP2(3,  QCU, XU##4,  XU##3 ) \
  STEP2(4,  QCU, XU##5,  XU##4 ) \
  STEP2(5,  QCU, XU##6,  XU##5 ) \
  STEP2(6,  QCU, XU##7,  XU##6 ) \
  STEP2(7,  QCU, XU##8,  XU##7 ) \
  STEP2(8,  QCU, XU##9,  XU##8 ) \
  STEP2(9,  QCU, XU##10, XU##9 ) \
  STEP2(10, QCU, XU##11, XU##10) \
  STEP2(11, QCU, XU##12, XU##11) \
  STEP2(12, QCU, XU##13, XU##12) \
  STEP2(13, QCU, XU##14, XU##13) \
  STEP2(14, QCU, XU##15, XU##14) \
  STEP2(15, QCU, XU##16, XU##15) \
  if (w < 3) { \
    if (t == 63) { \
      float2* pd = (float2*)&Mbx[w][16*cc + 2]; \
      pd[0] = make_float2(pb0,  pb1);  pd[1] = make_float2(pb2,  pb3); \
      pd[2] = make_float2(pb4,  pb5);  pd[3] = make_float2(pb6,  pb7); \
      pd[4] = make_float2(pb8,  pb9);  pd[5] = make_float2(pb10, pb11); \
      pd[6] = make_float2(pb12, pb13); pd[7] = make_float2(pb14, pb15); \
    } \
    __hip_atomic_store(&flagz[w], cc + 1, __ATOMIC_RELEASE, \
                       __HIP_MEMORY_SCOPE_WORKGROUP); \
  } }

__global__ __launch_bounds__(256, 1)
void sdtw_kernel(const float* __restrict__ input,
                 const float* __restrict__ target,
                 float* __restrict__ out) {
  const int b   = blockIdx.x;
  const int tid = threadIdx.x;        // 0..255; rows 2*tid, 2*tid+1
  const int t   = tid & 63;           // lane
  const int w   = tid >> 6;           // wave 0..3

  // Mdx[512+f] = dx[f] for f in [0,510]; zero pad elsewhere (780 f2).
  __shared__ __align__(8) float Mdx[1560];
  // Mbx[I][idx] = wave I lane63 nv_hi after step idx-2; row padded to 1092
  // so the conveyor's junk lanes (idx up to 16*63+1+63=1072) stay in-bounds.
  __shared__ __align__(8) float Mbx[3][1092];
  __shared__ int flagz[3];

  const float* __restrict__ inp = input + b * 512;
  const float* __restrict__ tgt = target + b * 512;

  for (int i = tid; i < 1560; i += 256) {
    float v = 0.0f;
    if (i >= 512 && i <= 1022) v = inp[i - 511] - inp[i - 512];
    Mdx[i] = v;
  }
  if (tid < 3) flagz[tid] = 0;
  if (tid < 6) Mbx[tid >> 1][tid & 1] = INF_F;  // prefill idx 0,1 per interface

  // dy for the two owned rows (row i uses dy[i-1] = tgt[i]-tgt[i-1])
  float dy_lo = (tid >= 1) ? (tgt[2*tid] - tgt[2*tid - 1]) : 0.0f;
  float dy_hi = tgt[2*tid + 1] - tgt[2*tid];

  // DP state @ chunk 0: r1 = diag d-1 (INF), r2_lo carries R[0][0]=0 seed.
  float r1_lo = INF_F, r1_hi = INF_F;
  float r2_lo = (tid == 0) ? 0.0f : INF_F;
  float SH2   = INF_F;
  float ans   = INF_F;
  int fcur = 0;

  float xa0,xa1,xa2,xa3,xa4,xa5,xa6,xa7,xa8,xa9;
  float xa10,xa11,xa12,xa13,xa14,xa15,xa16,xa17;
  float xb0,xb1,xb2,xb3,xb4,xb5,xb6,xb7,xb8,xb9;
  float xb10,xb11,xb12,xb13,xb14,xb15,xb16,xb17;
  float qca = INF_F, qcb = INF_F;     // conveyor regs (wave0 keeps INF)
  float pb0,pb1,pb2,pb3,pb4,pb5,pb6,pb7;
  float pb8,pb9,pb10,pb11,pb12,pb13,pb14,pb15;

  const float2* wbase2 = ((const float2*)Mdx) + (256 - tid);
  const float* qb_base = &Mbx[(w > 0) ? (w - 1) : 0][1 + t];

  __syncthreads();                    // staging + flag init visible

  // chunk-0 window
  { const float2* ip2 = wbase2;
    float2 a0=ip2[0],a1=ip2[1],a2=ip2[2],a3=ip2[3],a4=ip2[4];
    float2 a5=ip2[5],a6=ip2[6],a7=ip2[7],a8=ip2[8];
    xa0=a0.x;  xa1=a0.y;  xa2=a1.x;  xa3=a1.y;  xa4=a2.x;
    xa5=a2.y;  xa6=a3.x;  xa7=a3.y;  xa8=a4.x;  xa9=a4.y;
    xa10=a5.x; xa11=a5.y; xa12=a6.x; xa13=a6.y; xa14=a7.x;
    xa15=a7.y; xa16=a8.x; xa17=a8.y; }
  // chunk-0 conveyor: wait for producer chunk 0, load, sample fcur
  if (w > 0) {
    do { __builtin_amdgcn_s_sleep(1);
         fcur = __hip_atomic_load(&flagz[w-1], __ATOMIC_ACQUIRE,
                                  __HIP_MEMORY_SCOPE_WORKGROUP);
    } while (fcur < 1);
    asm volatile("" ::: "memory");
    qca = qb_base[0];
    fcur = __hip_atomic_load(&flagz[w-1], __ATOMIC_RELAXED,
                             __HIP_MEMORY_SCOPE_WORKGROUP);
  }

#pragma unroll 1
  for (int c = 0; c < 64; c += 2) {
    CHUNK(c,     xa, qca, xb, qcb)
    CHUNK(c + 1, xb, qcb, xa, qca)
  }

  // ans captured at cc=63, K=12 (step 1020, diag 1022) on row 511 = tid 255 hi
  if (tid == 255) {
    atomicAdd(out, ans * (1.0f / 64.0f));
  }
}

extern "C" void kernel_launch(void* const* d_in, const int* in_sizes, int n_in,
                              void* d_out, int out_size, void* d_ws, size_t ws_size,
                              hipStream_t stream) {
  const float* input  = (const float*)d_in[0];
  const float* target = (const float*)d_in[1];
  float* out = (float*)d_out;

  hipMemsetAsync(out, 0, sizeof(float), stream);
  sdtw_kernel<<<64, 256, 0, stream>>>(input, target, out);
}